// Round 8
// baseline (512.761 us; speedup 1.0000x reference)
//
#include <hip/hip_runtime.h>
#include <cstdint>
#include <cstddef>

// Problem constants (fixed shapes from setup_inputs)
#define IN_DIM  1024
#define OUT_DIM 1024
#define NB      7
#define KTOT    8192   // interleaved: k = i*8 + {x, basis0..basis6}
#define BROWS   8192   // batch

typedef unsigned short u16;
typedef __attribute__((ext_vector_type(8))) short bf16x8;
typedef __attribute__((ext_vector_type(8))) unsigned short u16x8;
typedef __attribute__((ext_vector_type(4))) float f32x4;

__device__ __forceinline__ u16 f2bf(float f) {
    union { float f; unsigned int u; } v; v.f = f;
    unsigned int r = (v.u + 0x7fffu + ((v.u >> 16) & 1u)) >> 16;  // RTN-even
    return (u16)r;
}

__device__ __forceinline__ void gl_lds16(const u16* g, u16* l) {
    __builtin_amdgcn_global_load_lds(
        (const __attribute__((address_space(1))) void*)g,
        (__attribute__((address_space(3))) void*)l,
        16, 0, 0);
}

// Shared by prep path and fused gemm: {x, basis0..6}(x) packed as 8 bf16.
// Identical math to the verified prep_a (bit-identical A values).
__device__ __forceinline__ u16x8 basis_pack(float xv) {
    float e = __expf(2.f * xv);
    float tv = 1.f - 2.f / (e + 1.f);            // tanh(xv)
    tv = fminf(fmaxf(tv, -1.f), 1.f);

    const float kn[11] = {-1.f, -0.8f, -0.6f, -0.4f, -0.2f, 0.f,
                           0.2f, 0.4f, 0.6f, 0.8f, 1.f};
    const float rcp[4] = {0.f, 5.f, 2.5f, 5.f / 3.f};  // 1/(0.2*d)
    float bb[8];
    #pragma unroll
    for (int j = 0; j < 7; ++j)
        bb[j] = (tv >= kn[j] && tv < kn[j + 1]) ? 1.f : 0.f;
    bb[7] = 0.f;
    #pragma unroll
    for (int d = 1; d <= 3; ++d) {
        #pragma unroll
        for (int j = 0; j < 7; ++j) {
            float left  = (tv - kn[j]) * rcp[d];
            float right = (kn[j + d + 1] - tv) * rcp[d];
            bb[j] = left * bb[j] + right * bb[j + 1];
        }
    }
    u16x8 outv;
    outv[0] = f2bf(xv);
    #pragma unroll
    for (int k = 0; k < NB; ++k) outv[1 + k] = f2bf(bb[k]);
    return outv;
}

// ---------------------------------------------------------------------------
// prep_wsw: Bt[o][i*8+0] = bf16(W[o][i]); Bt[o][i*8+1+k] = bf16(sw[i][o][k]).
__global__ __launch_bounds__(256) void prep_wsw(const float* __restrict__ sw,
                                                const float* __restrict__ W,
                                                u16* __restrict__ Bt) {
    __shared__ u16 S[8 * 256 * 8];               // [il][ol][slot], 32 KB
    const int i0 = blockIdx.x * 8;
    const int o0 = blockIdx.y * 256;
    const int t  = threadIdx.x;
    #pragma unroll
    for (int il = 0; il < 8; ++il) {
        const float* src = sw + ((size_t)(i0 + il) * OUT_DIM + o0) * NB;
        for (int c = t; c < 256 * NB; c += 256) {
            int ol = c / 7, k = c - ol * 7;
            S[(il * 256 + ol) * 8 + 1 + k] = f2bf(src[c]);
        }
    }
    for (int c = t; c < 2048; c += 256) {
        int ol = c >> 3, il = c & 7;
        S[(il * 256 + ol) * 8] = f2bf(W[(size_t)(o0 + ol) * IN_DIM + i0 + il]);
    }
    __syncthreads();
    for (int c = t; c < 2048; c += 256) {
        int ol = c >> 3, il = c & 7;   // consecutive t -> contiguous 16B writes
        *(u16x8*)&Bt[(size_t)(o0 + ol) * KTOT + (size_t)(i0 + il) * 8] =
            *(const u16x8*)&S[(il * 256 + ol) * 8];
    }
}

// ---------------------------------------------------------------------------
// gemm_fused v12 = v8's verified 128x128 skeleton (121 us, MfmaUtil 50,
// 0 conflicts) with A-generation FUSED into the staging phase:
//   Each v8 A-staging slot s = g*256+t held A[m0+32g+trow][chunk qsw] =
//   {x, basis0..6}(x[m0+32g+trow][ko/8 + qsw]) — exactly ONE x value.
//   So: load 4 x floats (lanes 0..7 read 32 contiguous bytes -> coalesced),
//   compute tanh+basis AFTER the MFMAs (x-load latency hidden by compute),
//   ds_write_b128 to the same swizzled slot in the next buffer.
// Kills: prep_a kernel (~40 us), 128 MB A write + 128 MB A read of HBM,
// one dispatch boundary, the A workspace (and chunking).
// A values bit-identical to prep_a -> C bit-identical to v8.
// Swizzle unchanged (verified family): phys_chunk(row, q) = q ^ (row & 7);
//   writer q = (t&7) ^ ((t>>3)&7); reader phys = (ks*4+qd) ^ (lm&7).
__global__ __launch_bounds__(256) void gemm_fused(const float* __restrict__ x,
                                                  const u16* __restrict__ Bt,
                                                  const float* __restrict__ bias,
                                                  float* __restrict__ C) {
    __shared__ __align__(16) u16 As[2][128 * 64];   // 2 x 16 KB
    __shared__ __align__(16) u16 Bs[2][128 * 64];   // 2 x 16 KB
    const int t = threadIdx.x;
    const int L = t & 63;
    const int w = t >> 6;
    const int wm = w & 1, wn = w >> 1;

    // XCD swizzle: blocks on one XCD share 8 m-tiles x 8 n-tiles; each
    // m-tile's 512 KB x-slice is L2-resident and reused by its 8 n-tiles.
    const int Lid = blockIdx.x;
    const int n_t = (Lid >> 3) & 7;
    const int m_t = (Lid & 7) + 8 * (Lid >> 6);
    const int m0 = m_t * 128;
    const int n0 = n_t * 128;

    f32x4 acc[4][4] = {};

    const int trow = t >> 3;                   // 0..31
    const int qsw  = (t & 7) ^ (trow & 7);     // logical chunk this thread owns
    const u16* gB[4];
    const float* gX[4];
    int off[4];
    #pragma unroll
    for (int g = 0; g < 4; ++g) {
        gB[g]  = Bt + (size_t)(n0 + 32 * g + trow) * KTOT + qsw * 8;
        gX[g]  = x  + (size_t)(m0 + 32 * g + trow) * IN_DIM + qsw;
        off[g] = (256 * g + t) * 8;            // 16B slot within one buffer
    }

    const int lm  = L & 15;
    const int qd  = L >> 4;                    // quad 0..3

    u16* pA  = &As[0][0];
    u16* pAn = &As[1][0];
    u16* pB  = &Bs[0][0];
    u16* pBn = &Bs[1][0];

    // prologue: stage tile 0 (B via DMA, A computed in-register)
    #pragma unroll
    for (int g = 0; g < 4; ++g) gl_lds16(gB[g], pB + off[g]);
    #pragma unroll
    for (int g = 0; g < 4; ++g)
        *(u16x8*)&pA[off[g]] = basis_pack(gX[g][0]);   // col = 0 + qsw
    __syncthreads();

    for (int ko = 0; ko < KTOT; ko += 64) {
        // issue next tile's B-DMA and x-loads FIRST (latency hidden by MFMAs)
        float xn[4];
        if (ko + 64 < KTOT) {
            #pragma unroll
            for (int g = 0; g < 4; ++g) gl_lds16(gB[g] + ko + 64, pBn + off[g]);
            const int cb = (ko + 64) >> 3;     // x column base for next tile
            #pragma unroll
            for (int g = 0; g < 4; ++g) xn[g] = gX[g][cb];
        }

        // compute current tile
        #pragma unroll
        for (int ks = 0; ks < 2; ++ks) {
            const int pq = ((ks * 4 + qd) ^ (lm & 7)) * 8;
            bf16x8 af[4], bfr[4];
            #pragma unroll
            for (int mi = 0; mi < 4; ++mi)
                af[mi] = *(const bf16x8*)&pA[(wm * 64 + mi * 16 + lm) * 64 + pq];
            #pragma unroll
            for (int ni = 0; ni < 4; ++ni)
                bfr[ni] = *(const bf16x8*)&pB[(wn * 64 + ni * 16 + lm) * 64 + pq];
            #pragma unroll
            for (int mi = 0; mi < 4; ++mi)
                #pragma unroll
                for (int ni = 0; ni < 4; ++ni)
                    acc[mi][ni] = __builtin_amdgcn_mfma_f32_16x16x32_bf16(
                        af[mi], bfr[ni], acc[mi][ni], 0, 0, 0);
        }

        // A-staging for next tile: basis compute + swizzled ds_write
        if (ko + 64 < KTOT) {
            #pragma unroll
            for (int g = 0; g < 4; ++g)
                *(u16x8*)&pAn[off[g]] = basis_pack(xn[g]);
        }

        // single barrier per K-step: drains B-DMA (vmcnt) + ds_writes (lgkm)
        // AFTER compute — next buffer ready, current safe to overwrite.
        __syncthreads();
        u16* tmp;
        tmp = pA; pA = pAn; pAn = tmp;
        tmp = pB; pB = pBn; pBn = tmp;
    }

    // epilogue: C/D layout col=lane&15, row=(lane>>4)*4+reg (m89-verified)
    const int r0 = qd * 4;
    #pragma unroll
    for (int ni = 0; ni < 4; ++ni) {
        int col = n0 + wn * 64 + ni * 16 + lm;
        float bv = bias[col];
        #pragma unroll
        for (int mi = 0; mi < 4; ++mi) {
            int rb = m0 + wm * 64 + mi * 16 + r0;
            f32x4 v = acc[mi][ni];
            #pragma unroll
            for (int rr = 0; rr < 4; ++rr)
                C[(size_t)(rb + rr) * OUT_DIM + col] = v[rr] + bv;
        }
    }
}

// ---------------------------------------------------------------------------
extern "C" void kernel_launch(void* const* d_in, const int* in_sizes, int n_in,
                              void* d_out, int out_size, void* d_ws, size_t ws_size,
                              hipStream_t stream) {
    (void)in_sizes; (void)n_in; (void)out_size; (void)ws_size;
    const float* x    = (const float*)d_in[0];
    const float* sw   = (const float*)d_in[1];
    const float* W    = (const float*)d_in[2];
    const float* bias = (const float*)d_in[3];
    float* out = (float*)d_out;

    u16* Bt = (u16*)d_ws;                      // 16 MB, only workspace user

    prep_wsw<<<dim3(IN_DIM / 8, OUT_DIM / 256), 256, 0, stream>>>(sw, W, Bt);
    gemm_fused<<<dim3(8 * (BROWS / 128)), 256, 0, stream>>>(x, Bt, bias, out);
}

// Round 9
// 360.313 us; speedup vs baseline: 1.4231x; 1.4231x over previous
//
#include <hip/hip_runtime.h>
#include <cstdint>
#include <cstddef>

// Problem constants (fixed shapes from setup_inputs)
#define IN_DIM  1024
#define OUT_DIM 1024
#define NB      7
#define KTOT    8192   // interleaved: k = i*8 + {x, basis0..basis6}
#define BROWS   8192   // batch

typedef unsigned short u16;
typedef __attribute__((ext_vector_type(8))) short bf16x8;
typedef __attribute__((ext_vector_type(8))) unsigned short u16x8;
typedef __attribute__((ext_vector_type(4))) float f32x4;

__device__ __forceinline__ u16 f2bf(float f) {
    union { float f; unsigned int u; } v; v.f = f;
    unsigned int r = (v.u + 0x7fffu + ((v.u >> 16) & 1u)) >> 16;  // RTN-even
    return (u16)r;
}

__device__ __forceinline__ void gl_lds16(const u16* g, u16* l) {
    __builtin_amdgcn_global_load_lds(
        (const __attribute__((address_space(1))) void*)g,
        (__attribute__((address_space(3))) void*)l,
        16, 0, 0);
}

// {x, basis0..6}(x) packed as 8 bf16 — identical math to the verified
// prep_a (bit-identical A values, reference-faithful truncated recursion).
__device__ __forceinline__ u16x8 basis_pack(float xv) {
    float e = __expf(2.f * xv);
    float tv = 1.f - 2.f / (e + 1.f);            // tanh(xv)
    tv = fminf(fmaxf(tv, -1.f), 1.f);

    const float kn[11] = {-1.f, -0.8f, -0.6f, -0.4f, -0.2f, 0.f,
                           0.2f, 0.4f, 0.6f, 0.8f, 1.f};
    const float rcp[4] = {0.f, 5.f, 2.5f, 5.f / 3.f};  // 1/(0.2*d)
    float bb[8];
    #pragma unroll
    for (int j = 0; j < 7; ++j)
        bb[j] = (tv >= kn[j] && tv < kn[j + 1]) ? 1.f : 0.f;
    bb[7] = 0.f;
    #pragma unroll
    for (int d = 1; d <= 3; ++d) {
        #pragma unroll
        for (int j = 0; j < 7; ++j) {
            float left  = (tv - kn[j]) * rcp[d];
            float right = (kn[j + d + 1] - tv) * rcp[d];
            bb[j] = left * bb[j] + right * bb[j + 1];
        }
    }
    u16x8 outv;
    outv[0] = f2bf(xv);
    #pragma unroll
    for (int k = 0; k < NB; ++k) outv[1 + k] = f2bf(bb[k]);
    return outv;
}

// ---------------------------------------------------------------------------
// prep_wsw: Bt[o][i*8+0] = bf16(W[o][i]); Bt[o][i*8+1+k] = bf16(sw[i][o][k]).
__global__ __launch_bounds__(256) void prep_wsw(const float* __restrict__ sw,
                                                const float* __restrict__ W,
                                                u16* __restrict__ Bt) {
    __shared__ u16 S[8 * 256 * 8];               // [il][ol][slot], 32 KB
    const int i0 = blockIdx.x * 8;
    const int o0 = blockIdx.y * 256;
    const int t  = threadIdx.x;
    #pragma unroll
    for (int il = 0; il < 8; ++il) {
        const float* src = sw + ((size_t)(i0 + il) * OUT_DIM + o0) * NB;
        for (int c = t; c < 256 * NB; c += 256) {
            int ol = c / 7, k = c - ol * 7;
            S[(il * 256 + ol) * 8 + 1 + k] = f2bf(src[c]);
        }
    }
    for (int c = t; c < 2048; c += 256) {
        int ol = c >> 3, il = c & 7;
        S[(il * 256 + ol) * 8] = f2bf(W[(size_t)(o0 + ol) * IN_DIM + i0 + il]);
    }
    __syncthreads();
    for (int c = t; c < 2048; c += 256) {
        int ol = c >> 3, il = c & 7;   // consecutive t -> contiguous 16B writes
        *(u16x8*)&Bt[(size_t)(o0 + ol) * KTOT + (size_t)(i0 + il) * 8] =
            *(const u16x8*)&S[(il * 256 + ol) * 8];
    }
}

// ---------------------------------------------------------------------------
// gemm_fused v13: fused A-generation at recompute factor F=4 (v12 was F=8
// and died on VALU: 66% busy, 474 us).
//   BM=128 x BN=256, 512 threads, 8 waves of 64x64 (2M x 4N).
//   Per thread per K-step: 2 basis_packs (A-tile 128x64 = 1024 x-values /
//   512 threads), placed after the MFMAs; x-loads issued before them.
//   Schedule = v8's verified single-barrier dbuf loop. LDS 96 KB, 1 blk/CU,
//   2 waves/SIMD (same effective concurrency as v8's 2 blocks x 4 waves).
// Eliminates the 128 MB A workspace -> harness re-poison drops ~80 us
// (measured: unaccounted 105 us @ 144 MB ws vs 25 us @ 16 MB ws).
// Swizzle = verified 8-chunk family (0 conflicts): writer slot s = 512g+t:
//   row = 64g + (t>>3), phys = t&7, logical q = (t&7) ^ ((t>>3)&7);
//   reader rows (wm*64|wn*64) + mi*16 + lm: row&7 == lm&7 ->
//   phys = (ks*4+qd) ^ (lm&7). All row offsets = 0 mod 8.
__global__ __launch_bounds__(512) void gemm_fused(const float* __restrict__ x,
                                                  const u16* __restrict__ Bt,
                                                  const float* __restrict__ bias,
                                                  float* __restrict__ C) {
    __shared__ __align__(16) u16 As[2][128 * 64];   // 2 x 16 KB
    __shared__ __align__(16) u16 Bs[2][256 * 64];   // 2 x 32 KB  (96 KB total)
    const int t = threadIdx.x;          // 0..511
    const int L = t & 63;
    const int w = t >> 6;               // 0..7
    const int wm = w & 1;               // m-half: rows wm*64
    const int wn = w >> 1;              // n-quarter: cols wn*64

    // XCD swizzle (bijective, 256 blocks): XCD x = Lid&7 owns m-tiles
    // m_t = x mod 8 family (8 m-tiles) x all 4 n-tiles = 32 blocks.
    // x-rows per XCD = 4 MB (L2-fit, reused by the 4 n-tiles).
    const int Lid = blockIdx.x;
    const int n_t = (Lid >> 3) & 3;
    const int m_t = (Lid & 7) + 8 * (Lid >> 5);
    const int m0 = m_t * 128;
    const int n0 = n_t * 256;

    f32x4 acc[4][4] = {};

    const int trow = t >> 3;                   // 0..63
    const int qsw  = (t & 7) ^ (trow & 7);     // logical chunk this thread owns
    const u16* gB[4];
    const float* gX[2];
    int offB[4], offA[2];
    #pragma unroll
    for (int g = 0; g < 4; ++g) {
        gB[g]  = Bt + (size_t)(n0 + 64 * g + trow) * KTOT + qsw * 8;
        offB[g] = (512 * g + t) * 8;           // 16B slot within one B buffer
    }
    #pragma unroll
    for (int g = 0; g < 2; ++g) {
        gX[g]  = x + (size_t)(m0 + 64 * g + trow) * IN_DIM + qsw;
        offA[g] = (512 * g + t) * 8;           // 16B slot within one A buffer
    }

    const int lm  = L & 15;
    const int qd  = L >> 4;                    // quad 0..3

    u16* pA  = &As[0][0];
    u16* pAn = &As[1][0];
    u16* pB  = &Bs[0][0];
    u16* pBn = &Bs[1][0];

    // prologue: stage tile 0 (B via DMA, A computed in-register)
    #pragma unroll
    for (int g = 0; g < 4; ++g) gl_lds16(gB[g], pB + offB[g]);
    #pragma unroll
    for (int g = 0; g < 2; ++g)
        *(u16x8*)&pA[offA[g]] = basis_pack(gX[g][0]);   // x column = 0 + qsw
    __syncthreads();

    for (int ko = 0; ko < KTOT; ko += 64) {
        // issue next tile's B-DMA and x-loads FIRST (latency hidden by MFMAs)
        float xn[2];
        if (ko + 64 < KTOT) {
            #pragma unroll
            for (int g = 0; g < 4; ++g) gl_lds16(gB[g] + ko + 64, pBn + offB[g]);
            const int cb = (ko + 64) >> 3;     // x column base for next tile
            #pragma unroll
            for (int g = 0; g < 2; ++g) xn[g] = gX[g][cb];
        }

        // compute current tile: 2 ks x (8 ds_read_b128 + 16 MFMA) per wave
        #pragma unroll
        for (int ks = 0; ks < 2; ++ks) {
            const int pq = ((ks * 4 + qd) ^ (lm & 7)) * 8;
            bf16x8 af[4], bfr[4];
            #pragma unroll
            for (int mi = 0; mi < 4; ++mi)
                af[mi] = *(const bf16x8*)&pA[(wm * 64 + mi * 16 + lm) * 64 + pq];
            #pragma unroll
            for (int ni = 0; ni < 4; ++ni)
                bfr[ni] = *(const bf16x8*)&pB[(wn * 64 + ni * 16 + lm) * 64 + pq];
            #pragma unroll
            for (int mi = 0; mi < 4; ++mi)
                #pragma unroll
                for (int ni = 0; ni < 4; ++ni)
                    acc[mi][ni] = __builtin_amdgcn_mfma_f32_16x16x32_bf16(
                        af[mi], bfr[ni], acc[mi][ni], 0, 0, 0);
        }

        // A-staging for next tile: basis compute + swizzled ds_write
        if (ko + 64 < KTOT) {
            #pragma unroll
            for (int g = 0; g < 2; ++g)
                *(u16x8*)&pAn[offA[g]] = basis_pack(xn[g]);
        }

        // single barrier per K-step: drains B-DMA (vmcnt) + A ds_writes
        // (lgkm) AFTER compute — next buffer ready, current safe to reuse.
        __syncthreads();
        u16* tmp;
        tmp = pA; pA = pAn; pAn = tmp;
        tmp = pB; pB = pBn; pBn = tmp;
    }

    // epilogue: C/D layout col=lane&15, row=(lane>>4)*4+reg (m89-verified)
    const int r0 = qd * 4;
    #pragma unroll
    for (int ni = 0; ni < 4; ++ni) {
        int col = n0 + wn * 64 + ni * 16 + lm;
        float bv = bias[col];
        #pragma unroll
        for (int mi = 0; mi < 4; ++mi) {
            int rb = m0 + wm * 64 + mi * 16 + r0;
            f32x4 v = acc[mi][ni];
            #pragma unroll
            for (int rr = 0; rr < 4; ++rr)
                C[(size_t)(rb + rr) * OUT_DIM + col] = v[rr] + bv;
        }
    }
}

// ---------------------------------------------------------------------------
extern "C" void kernel_launch(void* const* d_in, const int* in_sizes, int n_in,
                              void* d_out, int out_size, void* d_ws, size_t ws_size,
                              hipStream_t stream) {
    (void)in_sizes; (void)n_in; (void)out_size; (void)ws_size;
    const float* x    = (const float*)d_in[0];
    const float* sw   = (const float*)d_in[1];
    const float* W    = (const float*)d_in[2];
    const float* bias = (const float*)d_in[3];
    float* out = (float*)d_out;

    u16* Bt = (u16*)d_ws;                      // 16 MB, only workspace user

    prep_wsw<<<dim3(IN_DIM / 8, OUT_DIM / 256), 256, 0, stream>>>(sw, W, Bt);
    gemm_fused<<<dim3(256), 512, 0, stream>>>(x, Bt, bias, out);
}

// Round 10
// 309.952 us; speedup vs baseline: 1.6543x; 1.1625x over previous
//
#include <hip/hip_runtime.h>
#include <cstdint>
#include <cstddef>

// Problem constants (fixed shapes from setup_inputs)
#define IN_DIM  1024
#define OUT_DIM 1024
#define NB      7
#define KTOT    8192   // interleaved: k = i*8 + {x, basis0..basis6}
#define BROWS   8192   // batch

typedef unsigned short u16;
typedef __attribute__((ext_vector_type(8))) short bf16x8;
typedef __attribute__((ext_vector_type(8))) unsigned short u16x8;
typedef __attribute__((ext_vector_type(4))) float f32x4;

__device__ __forceinline__ u16 f2bf(float f) {
    union { float f; unsigned int u; } v; v.f = f;
    unsigned int r = (v.u + 0x7fffu + ((v.u >> 16) & 1u)) >> 16;  // RTN-even
    return (u16)r;
}

__device__ __forceinline__ void gl_lds16(const u16* g, u16* l) {
    __builtin_amdgcn_global_load_lds(
        (const __attribute__((address_space(1))) void*)g,
        (__attribute__((address_space(3))) void*)l,
        16, 0, 0);
}

// ---------------------------------------------------------------------------
// basis_pack v2: CLOSED FORM of the reference's truncated Cox-de Boor
// recursion (4x fewer VALU instructions than the recursion; v13 died on
// VALU at 59% busy).
// Derivation (verified against the recursion at f=0, f=0.5, knot seams,
// and the 0.4 boundary):
//  * degree-0 seeds exist only on intervals 0..6 ([kn_j, kn_{j+1}), kn_7=0.4)
//    -> for tv >= 0.4 the seed vector is empty -> ALL basis values == 0.
//  * for tv < 0.4: contributions flow only downward in index, never through
//    the truncated slot 7, so values equal the STANDARD uniform cubic
//    B-spline segment polys: with u=(tv+1)*5, j=floor(u), f=u-j:
//      b_j = B3 = f^3/6,  b_{j-1} = B2 = (-3f^3+3f^2+3f+1)/6,
//      b_{j-2} = B1 = (3f^3-6f^2+4)/6,  b_{j-3} = B0 = (1-f)^3/6,
//    (negative indices dropped; partition of unity holds interior).
//  * +-1ulp interval misclassification is harmless at interior knots (C^2
//    continuity: B-values match across the seam); the ONE discontinuity at
//    0.4 is guarded by an exact tv < 0.4f compare (same constant as the
//    verified kernel's kn[7]).
// Output u16x8 slots: [x, b0..b6]; words W0=(x,b0) W1=(b1,b2) W2=(b3,b4)
// W3=(b5,b6). Word tables over j (Z=0):
//   W1 = [Z,Q2,P1,Q1,P0,Q0,Z]  W2 = W1(j-2)  W3 = W1(j-4)  (+alive guard)
//   with P0=(B0,B1) P1=(B2,B3) Q0=(0,B0) Q1=(B1,B2) Q2=(B3,0).
__device__ __forceinline__ u16x8 basis_pack(float xv) {
    float e  = __expf(2.f * xv);
    float tv = 1.f - 2.f / (e + 1.f);            // tanh(xv)
    tv = fminf(fmaxf(tv, -1.f), 1.f);

    float u  = (tv + 1.f) * 5.f;
    float jf = fminf(__builtin_floorf(u), 6.f);
    float f  = u - jf;                           // local coord
    float f2 = f * f;
    const float s6 = 0.16666667f;
    float B3 = f * f2 * s6;
    float B2 = (((-3.f * f + 3.f) * f + 3.f) * f + 1.f) * s6;
    float B1 = ((3.f * f - 6.f) * f2 + 4.f) * s6;
    float om = 1.f - f;
    float B0 = om * om * om * s6;

    int  j     = (int)jf;                        // 0..6
    bool alive = tv < 0.4f;                      // exact truncation boundary

    unsigned int b0 = f2bf(B0), b1 = f2bf(B1), b2 = f2bf(B2), b3 = f2bf(B3);
    unsigned int P0 = b0 | (b1 << 16);
    unsigned int P1 = b2 | (b3 << 16);
    unsigned int Q0 = b0 << 16;
    unsigned int Q1 = b1 | (b2 << 16);
    unsigned int Q2 = b3;

    unsigned int W1 = (j < 4) ? ((j < 2) ? ((j < 1) ? 0u : Q2)
                                         : ((j < 3) ? P1 : Q1))
                              : ((j < 5) ? P0 : ((j < 6) ? Q0 : 0u));
    unsigned int W2 = (j < 3) ? 0u
                    : ((j < 4) ? Q2 : ((j < 5) ? P1
                    : ((j < 6) ? Q1 : (alive ? P0 : 0u))));
    unsigned int W3 = (j < 5) ? 0u : ((j < 6) ? Q2 : (alive ? P1 : 0u));
    unsigned int h0 = (j < 2) ? ((j < 1) ? b3 : b2)
                              : ((j < 3) ? b1 : ((j < 4) ? b0 : 0u));
    unsigned int W0 = (unsigned int)f2bf(xv) | (h0 << 16);

    union { unsigned int w[4]; u16x8 v; } r;
    r.w[0] = W0; r.w[1] = W1; r.w[2] = W2; r.w[3] = W3;
    return r.v;
}

// ---------------------------------------------------------------------------
// prep_wsw: Bt[o][i*8+0] = bf16(W[o][i]); Bt[o][i*8+1+k] = bf16(sw[i][o][k]).
__global__ __launch_bounds__(256) void prep_wsw(const float* __restrict__ sw,
                                                const float* __restrict__ W,
                                                u16* __restrict__ Bt) {
    __shared__ u16 S[8 * 256 * 8];               // [il][ol][slot], 32 KB
    const int i0 = blockIdx.x * 8;
    const int o0 = blockIdx.y * 256;
    const int t  = threadIdx.x;
    #pragma unroll
    for (int il = 0; il < 8; ++il) {
        const float* src = sw + ((size_t)(i0 + il) * OUT_DIM + o0) * NB;
        for (int c = t; c < 256 * NB; c += 256) {
            int ol = c / 7, k = c - ol * 7;
            S[(il * 256 + ol) * 8 + 1 + k] = f2bf(src[c]);
        }
    }
    for (int c = t; c < 2048; c += 256) {
        int ol = c >> 3, il = c & 7;
        S[(il * 256 + ol) * 8] = f2bf(W[(size_t)(o0 + ol) * IN_DIM + i0 + il]);
    }
    __syncthreads();
    for (int c = t; c < 2048; c += 256) {
        int ol = c >> 3, il = c & 7;   // consecutive t -> contiguous 16B writes
        *(u16x8*)&Bt[(size_t)(o0 + ol) * KTOT + (size_t)(i0 + il) * 8] =
            *(const u16x8*)&S[(il * 256 + ol) * 8];
    }
}

// ---------------------------------------------------------------------------
// gemm_fused v14 = v13 skeleton (verified correct: passed, 0 conflicts)
// with basis_pack swapped for the closed form. Nothing else changed.
//   BM=128 x BN=256, 512 threads, 8 waves of 64x64 (2M x 4N), F=4 recompute.
//   LDS 96 KB, 1 blk/CU, 2 waves/SIMD. No A workspace (re-poison killed).
// Swizzle = verified 8-chunk family (0 conflicts): writer slot s = 512g+t:
//   row = 64g + (t>>3), phys = t&7, logical q = (t&7) ^ ((t>>3)&7);
//   reader rows: row&7 == lm&7 -> phys = (ks*4+qd) ^ (lm&7).
__global__ __launch_bounds__(512) void gemm_fused(const float* __restrict__ x,
                                                  const u16* __restrict__ Bt,
                                                  const float* __restrict__ bias,
                                                  float* __restrict__ C) {
    __shared__ __align__(16) u16 As[2][128 * 64];   // 2 x 16 KB
    __shared__ __align__(16) u16 Bs[2][256 * 64];   // 2 x 32 KB  (96 KB total)
    const int t = threadIdx.x;          // 0..511
    const int L = t & 63;
    const int w = t >> 6;               // 0..7
    const int wm = w & 1;               // m-half: rows wm*64
    const int wn = w >> 1;              // n-quarter: cols wn*64

    // XCD swizzle (bijective, 256 blocks)
    const int Lid = blockIdx.x;
    const int n_t = (Lid >> 3) & 3;
    const int m_t = (Lid & 7) + 8 * (Lid >> 5);
    const int m0 = m_t * 128;
    const int n0 = n_t * 256;

    f32x4 acc[4][4] = {};

    const int trow = t >> 3;                   // 0..63
    const int qsw  = (t & 7) ^ (trow & 7);     // logical chunk this thread owns
    const u16* gB[4];
    const float* gX[2];
    int offB[4], offA[2];
    #pragma unroll
    for (int g = 0; g < 4; ++g) {
        gB[g]  = Bt + (size_t)(n0 + 64 * g + trow) * KTOT + qsw * 8;
        offB[g] = (512 * g + t) * 8;           // 16B slot within one B buffer
    }
    #pragma unroll
    for (int g = 0; g < 2; ++g) {
        gX[g]  = x + (size_t)(m0 + 64 * g + trow) * IN_DIM + qsw;
        offA[g] = (512 * g + t) * 8;           // 16B slot within one A buffer
    }

    const int lm  = L & 15;
    const int qd  = L >> 4;                    // quad 0..3

    u16* pA  = &As[0][0];
    u16* pAn = &As[1][0];
    u16* pB  = &Bs[0][0];
    u16* pBn = &Bs[1][0];

    // prologue: stage tile 0 (B via DMA, A computed in-register)
    #pragma unroll
    for (int g = 0; g < 4; ++g) gl_lds16(gB[g], pB + offB[g]);
    #pragma unroll
    for (int g = 0; g < 2; ++g)
        *(u16x8*)&pA[offA[g]] = basis_pack(gX[g][0]);   // x column = 0 + qsw
    __syncthreads();

    for (int ko = 0; ko < KTOT; ko += 64) {
        // issue next tile's B-DMA and x-loads FIRST (latency hidden by MFMAs)
        float xn[2];
        if (ko + 64 < KTOT) {
            #pragma unroll
            for (int g = 0; g < 4; ++g) gl_lds16(gB[g] + ko + 64, pBn + offB[g]);
            const int cb = (ko + 64) >> 3;     // x column base for next tile
            #pragma unroll
            for (int g = 0; g < 2; ++g) xn[g] = gX[g][cb];
        }

        // compute current tile: 2 ks x (8 ds_read_b128 + 16 MFMA) per wave
        #pragma unroll
        for (int ks = 0; ks < 2; ++ks) {
            const int pq = ((ks * 4 + qd) ^ (lm & 7)) * 8;
            bf16x8 af[4], bfr[4];
            #pragma unroll
            for (int mi = 0; mi < 4; ++mi)
                af[mi] = *(const bf16x8*)&pA[(wm * 64 + mi * 16 + lm) * 64 + pq];
            #pragma unroll
            for (int ni = 0; ni < 4; ++ni)
                bfr[ni] = *(const bf16x8*)&pB[(wn * 64 + ni * 16 + lm) * 64 + pq];
            #pragma unroll
            for (int mi = 0; mi < 4; ++mi)
                #pragma unroll
                for (int ni = 0; ni < 4; ++ni)
                    acc[mi][ni] = __builtin_amdgcn_mfma_f32_16x16x32_bf16(
                        af[mi], bfr[ni], acc[mi][ni], 0, 0, 0);
        }

        // A-staging for next tile: closed-form basis + swizzled ds_write
        if (ko + 64 < KTOT) {
            #pragma unroll
            for (int g = 0; g < 2; ++g)
                *(u16x8*)&pAn[offA[g]] = basis_pack(xn[g]);
        }

        // single barrier per K-step: drains B-DMA (vmcnt) + A ds_writes
        // (lgkm) AFTER compute — next buffer ready, current safe to reuse.
        __syncthreads();
        u16* tmp;
        tmp = pA; pA = pAn; pAn = tmp;
        tmp = pB; pB = pBn; pBn = tmp;
    }

    // epilogue: C/D layout col=lane&15, row=(lane>>4)*4+reg (m89-verified)
    const int r0 = qd * 4;
    #pragma unroll
    for (int ni = 0; ni < 4; ++ni) {
        int col = n0 + wn * 64 + ni * 16 + lm;
        float bv = bias[col];
        #pragma unroll
        for (int mi = 0; mi < 4; ++mi) {
            int rb = m0 + wm * 64 + mi * 16 + r0;
            f32x4 v = acc[mi][ni];
            #pragma unroll
            for (int rr = 0; rr < 4; ++rr)
                C[(size_t)(rb + rr) * OUT_DIM + col] = v[rr] + bv;
        }
    }
}

// ---------------------------------------------------------------------------
extern "C" void kernel_launch(void* const* d_in, const int* in_sizes, int n_in,
                              void* d_out, int out_size, void* d_ws, size_t ws_size,
                              hipStream_t stream) {
    (void)in_sizes; (void)n_in; (void)out_size; (void)ws_size;
    const float* x    = (const float*)d_in[0];
    const float* sw   = (const float*)d_in[1];
    const float* W    = (const float*)d_in[2];
    const float* bias = (const float*)d_in[3];
    float* out = (float*)d_out;

    u16* Bt = (u16*)d_ws;                      // 16 MB, only workspace user

    prep_wsw<<<dim3(IN_DIM / 8, OUT_DIM / 256), 256, 0, stream>>>(sw, W, Bt);
    gemm_fused<<<dim3(256), 512, 0, stream>>>(x, Bt, bias, out);
}